// Round 21
// baseline (272.985 us; speedup 1.0000x reference)
//
#include <hip/hip_runtime.h>
#include <hip/hip_bf16.h>

#define TB 2048
#define CC 1024
#define NH 16
#define HD 64
#define NB 4
#define BHX (NB*NH)    // 64
#define BTX (NB*TB)    // 8192

typedef __attribute__((ext_vector_type(8))) short bf16x8;
typedef __attribute__((ext_vector_type(4))) float f32x4;
typedef __attribute__((ext_vector_type(4))) unsigned short us4;

__device__ __forceinline__ unsigned short bfb(float f) {
  __hip_bfloat16 h = __float2bfloat16(f);
  return __builtin_bit_cast(unsigned short, h);
}
__device__ __forceinline__ float fexp2(float x) {
  return __builtin_amdgcn_exp2f(x);   // v_exp_f32 (2^x)
}
__device__ __forceinline__ unsigned cvtpk(float lo, float hi) {
  unsigned r;
  asm("v_cvt_pk_bf16_f32 %0, %1, %2" : "=v"(r) : "v"(lo), "v"(hi));
  return r;  // [15:0]=bf16(lo), [31:16]=bf16(hi)
}

__device__ __forceinline__ void gld_lds16(const void* g, void* l) {
  __builtin_amdgcn_global_load_lds(
      (const __attribute__((address_space(1))) unsigned*)g,
      (__attribute__((address_space(3))) unsigned*)l, 16, 0, 0);
}

__global__ void cvt_f32_bf16(const float* __restrict__ src,
                             unsigned short* __restrict__ dst, int n4) {
  int i = blockIdx.x * blockDim.x + threadIdx.x;
  if (i >= n4) return;
  f32x4 v = ((const f32x4*)src)[i];
  us4 o;
#pragma unroll
  for (int j = 0; j < 4; j++) o[j] = bfb(v[j]);
  ((us4*)dst)[i] = o;
}

// 4 weight matrices (1024x1024 f32 each) -> bf16, one launch.
__global__ void cvt_w4(const float* __restrict__ s0, const float* __restrict__ s1,
                       const float* __restrict__ s2, const float* __restrict__ s3,
                       unsigned short* __restrict__ d0, unsigned short* __restrict__ d1,
                       unsigned short* __restrict__ d2, unsigned short* __restrict__ d3) {
  int y = blockIdx.y;
  const float* s = y == 0 ? s0 : y == 1 ? s1 : y == 2 ? s2 : s3;
  unsigned short* d = y == 0 ? d0 : y == 1 ? d1 : y == 2 ? d2 : d3;
  int i = blockIdx.x * 256 + threadIdx.x;
  f32x4 v = ((const f32x4*)s)[i];
  us4 o;
#pragma unroll
  for (int j = 0; j < 4; j++) o[j] = bfb(v[j]);
  ((us4*)d)[i] = o;
}

__global__ void prep_bias(const float* __restrict__ bq, const float* __restrict__ bk,
                          const float* __restrict__ bv, float* __restrict__ out) {
  int i = blockIdx.x * 256 + threadIdx.x;   // grid 12*256 = 3072
  float v = i < 1024 ? bq[i] : i < 2048 ? bk[i - 1024] : bv[i - 2048];
  out[i] = v;
}

// C[i][n] = sum_k A[i][k]*Bw[n][k] + bias[n].  128x128 tile, BK=32, dbuf,
// single barrier per step, bijective XCD swizzle. 8 waves (512 thr),
// per-wave 64x32 output; launch_bounds(512,8) -> 4 blocks/CU (32 waves/CU).
// Conflict-free LDS XOR bijection on operand tiles (measured 0 conflicts).
// MODE 0: f32 output row-major [M][N] (coalesced 64B lines natively).
// MODE 1: bf16 scatter to qkv[part][bh][t][d] with RoPE on parts 0,1 --
// COALESCED via LDS: after the K-loop the (dead) Sm buffer is reused as a
// [128][128] bf16 tile (chunk-XOR swizzled, <=2-way banks); each thread then
// issues 4x 16B stores with consecutive lanes covering consecutive 16B
// chunks of a [t][d] row -> full-line writes, no RMW fetch.
template <int MODE>
__global__ __launch_bounds__(512, 8) void gemm_bt(
    const unsigned short* __restrict__ A, const unsigned short* __restrict__ Bw,
    const float* __restrict__ bias, const float* __restrict__ fcg,
    void* __restrict__ Cout, int M, int N, int K, int nbx)
{
  __shared__ __align__(16) unsigned short Sm[16384];  // 32KB: A0|B0|A1|B1
  int tid = threadIdx.x;                 // 0..511
  int lane = tid & 63, wid = tid >> 6;   // wid 0..7
  int g = lane >> 4, l4 = lane & 15;
  int wr = wid >> 2, wc = wid & 3;       // 2 M-halves x 4 N-quarters
  const int cpx = gridDim.x >> 3;
  const int swz = (blockIdx.x & 7) * cpx + (blockIdx.x >> 3);
  const int bx = swz % nbx, by = swz / nbx;
  const int brow = by * 128, bcol = bx * 128;

  // staging source (row, chunk) for linear dest chunk c = tid
  const int s0 = (tid & 7) ^ ((tid >> 3) & 7);
  const int r0 = ((tid >> 3) << 1) | (s0 >> 2), g0 = s0 & 3;
  const unsigned short* a0 = A + (size_t)(brow + r0) * K + g0 * 8;
  const unsigned short* b0 = Bw + (size_t)(bcol + r0) * K + g0 * 8;
  const int lo = tid * 8;

  // fragment read offsets (loop-invariant, swizzled)
  int aoff[4], boff[2];
#pragma unroll
  for (int i = 0; i < 4; i++) {
    int ra = wr * 64 + i * 16 + l4;
    aoff[i] = (ra >> 1) * 64 + (((((ra & 1) << 2) | g) ^ ((ra >> 1) & 7)) * 8);
  }
#pragma unroll
  for (int i = 0; i < 2; i++) {
    int rb = wc * 32 + i * 16 + l4;
    boff[i] = (rb >> 1) * 64 + (((((rb & 1) << 2) | g) ^ ((rb >> 1) & 7)) * 8);
  }

  f32x4 acc[4][2] = {};

  // Prologue: stage K-step 0 into buffer 0.
  gld_lds16(a0, &Sm[lo]);
  gld_lds16(b0, &Sm[4096 + lo]);
  a0 += 32; b0 += 32;
  __syncthreads();   // auto vmcnt(0): buf0 ready

  const int nk = K >> 5;
  for (int kk = 0; kk < nk; kk++) {
    const int cur = kk & 1;
    if (kk + 1 < nk) {   // issue next step's loads; they fly during compute
      const int nb = (cur ^ 1) * 8192;
      gld_lds16(a0, &Sm[nb + lo]);
      gld_lds16(b0, &Sm[nb + 4096 + lo]);
      a0 += 32; b0 += 32;
    }
    const unsigned short* Ac = &Sm[cur * 8192];
    const unsigned short* Bc = &Sm[cur * 8192 + 4096];
    bf16x8 af[4], bfr[2];
#pragma unroll
    for (int i = 0; i < 4; i++)
      af[i] = *(const bf16x8*)&Ac[aoff[i]];
#pragma unroll
    for (int i = 0; i < 2; i++)
      bfr[i] = *(const bf16x8*)&Bc[boff[i]];
    __builtin_amdgcn_s_setprio(1);
#pragma unroll
    for (int i = 0; i < 4; i++)
#pragma unroll
      for (int j = 0; j < 2; j++)
        acc[i][j] = __builtin_amdgcn_mfma_f32_16x16x32_bf16(af[i], bfr[j], acc[i][j], 0, 0, 0);
    __builtin_amdgcn_s_setprio(0);
    __syncthreads();
  }

  if (MODE == 0) {
    float* out = (float*)Cout;
#pragma unroll
    for (int i = 0; i < 4; i++) {
      int grow0 = brow + wr * 64 + i * 16 + 4 * g;
#pragma unroll
      for (int j = 0; j < 2; j++) {
        int gcol = bcol + wc * 32 + j * 16 + l4;
        float bv = bias[gcol];
#pragma unroll
        for (int r = 0; r < 4; r++)
          out[(size_t)(grow0 + r) * N + gcol] = acc[i][j][r] + bv;
      }
    }
  } else {
    // Stage roped/biased bf16 output into Sm as [rl][cl] 128x128 tile,
    // chunk-XOR swizzled: pc = (cl&7) | (((cl>>3) ^ ((rl>>2)&15)) << 3).
#pragma unroll
    for (int i = 0; i < 4; i++) {
      int rl0 = wr * 64 + i * 16 + 4 * g;
#pragma unroll
      for (int j = 0; j < 2; j++) {
        int cl = wc * 32 + j * 16 + l4;
        int gcol = bcol + cl;
        float bv = bias[gcol];
        int cc2 = gcol & 1023;
        int d = cc2 & 63;
        int dbase = d & ~1;
        float sgn = (d & 1) ? 1.f : -1.f;
        bool isqk = (gcol >> 10) < 2;   // uniform across the l4/l4^1 pair
#pragma unroll
        for (int r = 0; r < 4; r++) {
          int rl = rl0 + r;
          int t = (brow + rl) & 2047;
          float v = acc[i][j][r] + bv;
          float w = __shfl_xor(v, 1, 64);  // partner dim's value
          float o = v;
          if (isqk) {
            float cth = fcg[(size_t)t * 64 + dbase];
            float sth = fcg[(size_t)t * 64 + dbase + 1];
            o = v * cth + sgn * w * sth;
          }
          int pc = (cl & 7) | ((((cl >> 3) ^ (rl >> 2)) & 15) << 3);
          Sm[rl * 128 + pc] = bfb(o);
        }
      }
    }
    __syncthreads();
    // Coalesced 16B stores: chunk = s2*512 + tid; consecutive lanes cover
    // consecutive 16B chunks of a [t][d] row (full 64B+ lines).
    unsigned short* out = (unsigned short*)Cout;
#pragma unroll
    for (int s2 = 0; s2 < 4; s2++) {
      int chunk = s2 * 512 + tid;
      int rl = chunk >> 4, kch = chunk & 15;
      int pk = kch ^ ((rl >> 2) & 15);
      int gcol = bcol + kch * 8;
      int part = gcol >> 10;
      int cc2 = gcol & 1023;
      int h = cc2 >> 6, d = cc2 & 63;
      int grow = brow + rl;
      int b = grow >> 11, t = grow & 2047;
      size_t dst = (size_t)part * ((size_t)BHX * TB * HD)
                 + ((size_t)(b * NH + h) * TB + t) * HD + d;
      *(bf16x8*)&out[dst] = *(const bf16x8*)&Sm[rl * 128 + pk * 8];
    }
  }
}

// v [bh][T][64] -> vT [bh][64][T], 64x64 tiles. 256 threads, 2 chunks each way.
__global__ void transpose_v(const unsigned short* __restrict__ v,
                            unsigned short* __restrict__ vT) {
  int bh = blockIdx.y, t0 = blockIdx.x * 64;
  __shared__ __align__(16) unsigned short tile[64][72];
  int tid = threadIdx.x;
#pragma unroll
  for (int s = 0; s < 2; s++) {
    int cid = tid + 256 * s;
    int r = cid >> 3, c8 = (cid & 7) * 8;
    bf16x8 val = *(const bf16x8*)(v + ((size_t)bh * TB + t0 + r) * HD + c8);
    *(bf16x8*)&tile[r][c8] = val;
  }
  __syncthreads();
#pragma unroll
  for (int s = 0; s < 2; s++) {
    int cid = tid + 256 * s;
    int rr = cid >> 3, cc = (cid & 7) * 8;
    bf16x8 o;
#pragma unroll
    for (int i = 0; i < 8; i++) o[i] = (short)tile[cc + i][rr];
    *(bf16x8*)(vT + ((size_t)bh * HD + rr) * TB + t0 + cc) = o;
  }
}

// Flash attention fwd, causal. STATIC XCD-affine schedule.
// SWAPPED QK^T (T12 enabler): z = mfma(K, Q) -> lane holds 16 kv-samples of
// its OWN q-row (q = l4). Row max = lane tree + 2 shfl_xor; m/l/alpha are
// scalars; row-sum cross-lane reduce deferred to epilogue. P packed with
// v_cvt_pk_bf16_f32 and written as 4x ds_write_b64 into Ps[q=l4][kv] with
// 16B-slot-pair XOR (l4&7); PV = mfma(V^T-frag, P-frag) accumulating O^T
// (col=q), epilogue packs 4 consecutive d as one 8B store.
__global__ __launch_bounds__(256, 4) void flash_fwd(
    const unsigned short* __restrict__ q, const unsigned short* __restrict__ k,
    const unsigned short* __restrict__ vT, unsigned short* __restrict__ yb)
{
  __shared__ __align__(16) unsigned short Ks[2][4096];
  __shared__ __align__(16) unsigned short Vs[2][4096];
  __shared__ __align__(16) unsigned short Ps[4][16][64];  // [wave][q=l4][kv swz]

  const int tid = threadIdx.x, wid = tid >> 6, lane = tid & 63;
  const int g = lane >> 4, l4 = lane & 15;

  const int b = blockIdx.x;
  const int xcd = b & 7;
  const int idx = b >> 3;
  const int bh = (xcd << 3) | (idx & 7);
  const int pr = idx >> 3;

  const int off0 = tid << 4;
  const int row0 = off0 >> 7, sc0 = ((off0 >> 4) & 7) ^ (row0 & 7);
  const int off1 = off0 + 4096;
  const int row1 = off1 >> 7, sc1 = ((off1 >> 4) & 7) ^ (row1 & 7);
  const int koff0 = (row0 << 6) + (sc0 << 3);
  const int koff1 = (row1 << 6) + (sc1 << 3);
  const int voff0 = (row0 << 11) + (sc0 << 3);
  const int voff1 = (row1 << 11) + (sc1 << 3);

  const float SCL2 = 0.18033688011112042f;  // 1/8 * log2(e)
  const int l7 = l4 & 7;

  unsigned short* psrow = &Ps[wid][l4][0];
  const int woff0 = ((0 + (g >> 1)) ^ l7) * 8 + (g & 1) * 4;  // cb=0
  const int woff1 = ((2 + (g >> 1)) ^ l7) * 8 + (g & 1) * 4;  // cb=1
  const int woff2 = ((4 + (g >> 1)) ^ l7) * 8 + (g & 1) * 4;  // cb=2
  const int woff3 = ((6 + (g >> 1)) ^ l7) * 8 + (g & 1) * 4;  // cb=3
  const int roff0 = (g ^ l7) * 8;
  const int roff1 = ((4 + g) ^ l7) * 8;

  const unsigned short* kb = k  + ((size_t)bh << 17);
  const unsigned short* vb = vT + ((size_t)bh << 17);

#pragma unroll 1
  for (int sel = 0; sel < 2; sel++) {
    const int q64 = sel ? (31 - pr) : pr;
    const int qrow = q64 * 64 + wid * 16 + l4;

    bf16x8 qf0, qf1;
    {
      const unsigned short* qp = q + (((size_t)bh * TB + qrow) << 6);
      qf0 = *(const bf16x8*)(qp + g * 8);
      qf1 = *(const bf16x8*)(qp + 32 + g * 8);
    }

    float m_run = -1e30f, l_run = 0.f;
    f32x4 acc_o[4] = {};

    gld_lds16(kb + koff0, &Ks[0][off0 >> 1]);
    gld_lds16(kb + koff1, &Ks[0][off1 >> 1]);
    gld_lds16(vb + voff0, &Vs[0][off0 >> 1]);
    gld_lds16(vb + voff1, &Vs[0][off1 >> 1]);
    __syncthreads();

    for (int kt = 0; kt <= q64; kt++) {
      const int cur = kt & 1;
      if (kt < q64) {
        const int kadd = (kt + 1) << 12;
        const int vadd = (kt + 1) << 6;
        gld_lds16(kb + koff0 + kadd, &Ks[cur ^ 1][off0 >> 1]);
        gld_lds16(kb + koff1 + kadd, &Ks[cur ^ 1][off1 >> 1]);
        gld_lds16(vb + voff0 + vadd, &Vs[cur ^ 1][off0 >> 1]);
        gld_lds16(vb + voff1 + vadd, &Vs[cur ^ 1][off1 >> 1]);
      }
      const unsigned short* Kc = Ks[cur];
      const unsigned short* Vc = Vs[cur];

      // S^T = K Q^T: lane holds S[q=own row][kv = 16cb+4g+j].
      float sv[4][4];
      __builtin_amdgcn_s_setprio(1);
#pragma unroll
      for (int cb = 0; cb < 4; cb++) {
        const int r = cb * 16 + l4;
        const int sw = (r & 7) * 8;
        bf16x8 kb0 = *(const bf16x8*)&Kc[r * 64 + ((g * 8) ^ sw)];
        bf16x8 kb1 = *(const bf16x8*)&Kc[r * 64 + (((g + 4) * 8) ^ sw)];
        f32x4 z = {0.f, 0.f, 0.f, 0.f};
        z = __builtin_amdgcn_mfma_f32_16x16x32_bf16(kb0, qf0, z, 0, 0, 0);
        z = __builtin_amdgcn_mfma_f32_16x16x32_bf16(kb1, qf1, z, 0, 0, 0);
#pragma unroll
        for (int j = 0; j < 4; j++)
          sv[cb][j] = z[j] * SCL2;
      }
      __builtin_amdgcn_s_setprio(0);
      if (kt == q64) {   // diagonal tile: mask kv > q  <=>  16cb+4g+j > wid*16+l4
        const int rq = wid * 16 + l4;
#pragma unroll
        for (int cb = 0; cb < 4; cb++)
#pragma unroll
          for (int j = 0; j < 4; j++)
            if (cb * 16 + 4 * g + j > rq) sv[cb][j] = -1e30f;
      }

      // Row max: lane-local tree + 2 shfl_xor across g-groups.
      float mt;
      {
        float m0 = fmaxf(fmaxf(sv[0][0], sv[0][1]), fmaxf(sv[0][2], sv[0][3]));
        float m1 = fmaxf(fmaxf(sv[1][0], sv[1][1]), fmaxf(sv[1][2], sv[1][3]));
        float m2 = fmaxf(fmaxf(sv[2][0], sv[2][1]), fmaxf(sv[2][2], sv[2][3]));
        float m3 = fmaxf(fmaxf(sv[3][0], sv[3][1]), fmaxf(sv[3][2], sv[3][3]));
        mt = fmaxf(fmaxf(m0, m1), fmaxf(m2, m3));
        mt = fmaxf(mt, __shfl_xor(mt, 16, 64));
        mt = fmaxf(mt, __shfl_xor(mt, 32, 64));
      }
      // Defer-max: rescale only when max grew by > 8 (log2 domain).
      bool need = mt > m_run + 8.f;
      if (__any(need)) {
        float mn = fmaxf(m_run, mt);
        float alpha = fexp2(m_run - mn);
        m_run = mn;
        l_run *= alpha;
#pragma unroll
        for (int db = 0; db < 4; db++)
#pragma unroll
          for (int j = 0; j < 4; j++) acc_o[db][j] *= alpha;
      }
      // exp + lane-local sum; pack P and write 4x ds_write_b64.
      float lsum = 0.f;
#pragma unroll
      for (int cb = 0; cb < 4; cb++) {
        float p0 = fexp2(sv[cb][0] - m_run);
        float p1 = fexp2(sv[cb][1] - m_run);
        float p2 = fexp2(sv[cb][2] - m_run);
        float p3 = fexp2(sv[cb][3] - m_run);
        lsum += (p0 + p1) + (p2 + p3);
        uint2 w;
        w.x = cvtpk(p0, p1);
        w.y = cvtpk(p2, p3);
        const int wo = (cb == 0) ? woff0 : (cb == 1) ? woff1 : (cb == 2) ? woff2 : woff3;
        *(uint2*)&psrow[wo] = w;
      }
      l_run += lsum;

      asm volatile("s_waitcnt lgkmcnt(0)" ::: "memory");
      __builtin_amdgcn_sched_barrier(0);
      bf16x8 pb0 = *(const bf16x8*)&psrow[roff0];
      bf16x8 pb1 = *(const bf16x8*)&psrow[roff1];
      __builtin_amdgcn_s_setprio(1);
#pragma unroll
      for (int db = 0; db < 4; db++) {
        const int r = db * 16 + l4;
        const int sw = (r & 7) * 8;
        bf16x8 vb0 = *(const bf16x8*)&Vc[r * 64 + ((g * 8) ^ sw)];
        bf16x8 vb1 = *(const bf16x8*)&Vc[r * 64 + (((g + 4) * 8) ^ sw)];
        acc_o[db] = __builtin_amdgcn_mfma_f32_16x16x32_bf16(vb0, pb0, acc_o[db], 0, 0, 0);
        acc_o[db] = __builtin_amdgcn_mfma_f32_16x16x32_bf16(vb1, pb1, acc_o[db], 0, 0, 0);
      }
      __builtin_amdgcn_s_setprio(0);
      __syncthreads();
    }

    // Epilogue: finish l across g-groups, normalize, write O^T rows.
    float l = l_run;
    l += __shfl_xor(l, 16, 64);
    l += __shfl_xor(l, 32, 64);
    const float inv = 1.0f / l;
    unsigned short* yp = yb + ((size_t)(bh >> 4) * TB) * CC + (size_t)(bh & 15) * HD;
#pragma unroll
    for (int db = 0; db < 4; db++) {
      us4 ov;
#pragma unroll
      for (int j = 0; j < 4; j++) ov[j] = bfb(acc_o[db][j] * inv);
      *(us4*)&yp[(size_t)qrow * CC + db * 16 + 4 * g] = ov;
    }
  }
}

extern "C" void kernel_launch(void* const* d_in, const int* in_sizes, int n_in,
                              void* d_out, int out_size, void* d_ws, size_t ws_size,
                              hipStream_t stream) {
  (void)in_sizes; (void)n_in; (void)out_size; (void)ws_size;
  const float* x  = (const float*)d_in[0];
  const float* fc = (const float*)d_in[1];
  // d_in[2]=attn_mask (tril), d_in[3]=padding_mask (all ones): applied analytically.
  const float* Wq = (const float*)d_in[4];
  const float* bq = (const float*)d_in[5];
  const float* Wk = (const float*)d_in[6];
  const float* bk = (const float*)d_in[7];
  const float* Wv = (const float*)d_in[8];
  const float* bv = (const float*)d_in[9];
  const float* Wp = (const float*)d_in[10];
  const float* bp = (const float*)d_in[11];

  char* ws = (char*)d_ws;
  unsigned short* xb   = (unsigned short*)(ws + 0);          // 8192x1024 bf16 (later reused as yb)
  unsigned short* wqkv = (unsigned short*)(ws + 16777216);   // 3072x1024 bf16
  unsigned short* wp   = (unsigned short*)(ws + 23068672);   // 1024x1024 bf16
  float*          bqkv = (float*)(ws + 25165824);            // 3072 f32
  unsigned short* qkv  = (unsigned short*)(ws + 25182208);   // 3 x [64][2048][64] bf16
  unsigned short* vT   = qkv + 3 * (size_t)8388608;          // [64][64][2048] bf16
  unsigned short* yb   = xb;

  cvt_f32_bf16<<<(2097152 + 255) / 256, 256, 0, stream>>>(x, xb, 2097152);
  cvt_w4<<<dim3(1024, 4), 256, 0, stream>>>(Wq, Wk, Wv, Wp,
      wqkv, wqkv + 1048576, wqkv + 2097152, wp);
  prep_bias<<<dim3(12), 256, 0, stream>>>(bq, bk, bv, bqkv);

  gemm_bt<1><<<dim3(1536), 512, 0, stream>>>(xb, wqkv, bqkv, fc, qkv, BTX, 3072, 1024, 24);
  transpose_v<<<dim3(32, 64), 256, 0, stream>>>(qkv + 2 * (size_t)8388608, vT);
  flash_fwd<<<dim3(1024), 256, 0, stream>>>(qkv, qkv + (size_t)8388608, vT, yb);
  gemm_bt<0><<<dim3(512), 512, 0, stream>>>(yb, wp, bp, nullptr, (float*)d_out, BTX, 1024, 1024, 8);
}

// Round 22
// 200.042 us; speedup vs baseline: 1.3646x; 1.3646x over previous
//
#include <hip/hip_runtime.h>
#include <hip/hip_bf16.h>

#define TB 2048
#define CC 1024
#define NH 16
#define HD 64
#define NB 4
#define BHX (NB*NH)    // 64
#define BTX (NB*TB)    // 8192

typedef __attribute__((ext_vector_type(8))) short bf16x8;
typedef __attribute__((ext_vector_type(4))) float f32x4;
typedef __attribute__((ext_vector_type(4))) unsigned short us4;

__device__ __forceinline__ unsigned short bfb(float f) {
  __hip_bfloat16 h = __float2bfloat16(f);
  return __builtin_bit_cast(unsigned short, h);
}
__device__ __forceinline__ float fexp2(float x) {
  return __builtin_amdgcn_exp2f(x);   // v_exp_f32 (2^x)
}
__device__ __forceinline__ unsigned cvtpk(float lo, float hi) {
  unsigned r;
  asm("v_cvt_pk_bf16_f32 %0, %1, %2" : "=v"(r) : "v"(lo), "v"(hi));
  return r;  // [15:0]=bf16(lo), [31:16]=bf16(hi)
}

__device__ __forceinline__ void gld_lds16(const void* g, void* l) {
  __builtin_amdgcn_global_load_lds(
      (const __attribute__((address_space(1))) unsigned*)g,
      (__attribute__((address_space(3))) unsigned*)l, 16, 0, 0);
}

__global__ void cvt_f32_bf16(const float* __restrict__ src,
                             unsigned short* __restrict__ dst, int n4) {
  int i = blockIdx.x * blockDim.x + threadIdx.x;
  if (i >= n4) return;
  f32x4 v = ((const f32x4*)src)[i];
  us4 o;
#pragma unroll
  for (int j = 0; j < 4; j++) o[j] = bfb(v[j]);
  ((us4*)dst)[i] = o;
}

// 4 weight matrices (1024x1024 f32 each) -> bf16, one launch.
__global__ void cvt_w4(const float* __restrict__ s0, const float* __restrict__ s1,
                       const float* __restrict__ s2, const float* __restrict__ s3,
                       unsigned short* __restrict__ d0, unsigned short* __restrict__ d1,
                       unsigned short* __restrict__ d2, unsigned short* __restrict__ d3) {
  int y = blockIdx.y;
  const float* s = y == 0 ? s0 : y == 1 ? s1 : y == 2 ? s2 : s3;
  unsigned short* d = y == 0 ? d0 : y == 1 ? d1 : y == 2 ? d2 : d3;
  int i = blockIdx.x * 256 + threadIdx.x;
  f32x4 v = ((const f32x4*)s)[i];
  us4 o;
#pragma unroll
  for (int j = 0; j < 4; j++) o[j] = bfb(v[j]);
  ((us4*)d)[i] = o;
}

__global__ void prep_bias(const float* __restrict__ bq, const float* __restrict__ bk,
                          const float* __restrict__ bv, float* __restrict__ out) {
  int i = blockIdx.x * 256 + threadIdx.x;   // grid 12*256 = 3072
  float v = i < 1024 ? bq[i] : i < 2048 ? bk[i - 1024] : bv[i - 2048];
  out[i] = v;
}

// C[i][n] = sum_k A[i][k]*Bw[n][k] + bias[n].  128x128 tile, BK=32, dbuf,
// single barrier per step, bijective XCD swizzle. 8 waves (512 thr),
// per-wave 64x32 output; launch_bounds(512,8) -> 4 blocks/CU (32 waves/CU).
// Conflict-free LDS XOR bijection (measured 0 conflicts).
// MODE 0: f32 output row-major [M][N]. MODE 1: bf16 scatter to
// qkv[part][bh][t][d] with RoPE on parts 0,1 via shfl partner exchange.
template <int MODE>
__global__ __launch_bounds__(512, 8) void gemm_bt(
    const unsigned short* __restrict__ A, const unsigned short* __restrict__ Bw,
    const float* __restrict__ bias, const float* __restrict__ fcg,
    void* __restrict__ Cout, int M, int N, int K, int nbx)
{
  __shared__ __align__(16) unsigned short As[2][4096];
  __shared__ __align__(16) unsigned short Bs[2][4096];
  int tid = threadIdx.x;                 // 0..511
  int lane = tid & 63, wid = tid >> 6;   // wid 0..7
  int g = lane >> 4, l4 = lane & 15;
  int wr = wid >> 2, wc = wid & 3;       // 2 M-halves x 4 N-quarters
  const int cpx = gridDim.x >> 3;
  const int swz = (blockIdx.x & 7) * cpx + (blockIdx.x >> 3);
  const int bx = swz % nbx, by = swz / nbx;
  const int brow = by * 128, bcol = bx * 128;

  // staging source (row, chunk) for linear dest chunk c = tid
  const int s0 = (tid & 7) ^ ((tid >> 3) & 7);
  const int r0 = ((tid >> 3) << 1) | (s0 >> 2), g0 = s0 & 3;
  const unsigned short* a0 = A + (size_t)(brow + r0) * K + g0 * 8;
  const unsigned short* b0 = Bw + (size_t)(bcol + r0) * K + g0 * 8;
  const int lo = tid * 8;

  // fragment read offsets (loop-invariant, swizzled)
  int aoff[4], boff[2];
#pragma unroll
  for (int i = 0; i < 4; i++) {
    int ra = wr * 64 + i * 16 + l4;
    aoff[i] = (ra >> 1) * 64 + (((((ra & 1) << 2) | g) ^ ((ra >> 1) & 7)) * 8);
  }
#pragma unroll
  for (int i = 0; i < 2; i++) {
    int rb = wc * 32 + i * 16 + l4;
    boff[i] = (rb >> 1) * 64 + (((((rb & 1) << 2) | g) ^ ((rb >> 1) & 7)) * 8);
  }

  f32x4 acc[4][2] = {};

  // Prologue: stage K-step 0 into buffer 0.
  gld_lds16(a0, &As[0][lo]);
  gld_lds16(b0, &Bs[0][lo]);
  a0 += 32; b0 += 32;
  __syncthreads();   // auto vmcnt(0): buf0 ready

  const int nk = K >> 5;
  for (int kk = 0; kk < nk; kk++) {
    const int cur = kk & 1;
    if (kk + 1 < nk) {   // issue next step's loads; they fly during compute
      gld_lds16(a0, &As[cur ^ 1][lo]);
      gld_lds16(b0, &Bs[cur ^ 1][lo]);
      a0 += 32; b0 += 32;
    }
    bf16x8 af[4], bfr[2];
#pragma unroll
    for (int i = 0; i < 4; i++)
      af[i] = *(const bf16x8*)&As[cur][aoff[i]];
#pragma unroll
    for (int i = 0; i < 2; i++)
      bfr[i] = *(const bf16x8*)&Bs[cur][boff[i]];
    __builtin_amdgcn_s_setprio(1);
#pragma unroll
    for (int i = 0; i < 4; i++)
#pragma unroll
      for (int j = 0; j < 2; j++)
        acc[i][j] = __builtin_amdgcn_mfma_f32_16x16x32_bf16(af[i], bfr[j], acc[i][j], 0, 0, 0);
    __builtin_amdgcn_s_setprio(0);
    __syncthreads();
  }

#pragma unroll
  for (int i = 0; i < 4; i++) {
    int grow0 = brow + wr * 64 + i * 16 + 4 * g;
#pragma unroll
    for (int j = 0; j < 2; j++) {
      int gcol = bcol + wc * 32 + j * 16 + l4;
      float bv = bias[gcol];
      if (MODE == 0) {
        float* out = (float*)Cout;
#pragma unroll
        for (int r = 0; r < 4; r++)
          out[(size_t)(grow0 + r) * N + gcol] = acc[i][j][r] + bv;
      } else {
        unsigned short* out = (unsigned short*)Cout;
        int part = gcol >> 10;
        int c = gcol & 1023;
        int h = c >> 6, d = c & 63;
        int dbase = d & ~1;
        float sgn = (d & 1) ? 1.f : -1.f;
        bool isqk = (part < 2);   // uniform across the l4/l4^1 pair
#pragma unroll
        for (int r = 0; r < 4; r++) {
          int grow = grow0 + r;
          int b = grow >> 11, t = grow & 2047;
          float v = acc[i][j][r] + bv;
          float w = __shfl_xor(v, 1, 64);  // partner dim's value
          float o = v;
          if (isqk) {
            float cth = fcg[(size_t)t * 64 + dbase];
            float sth = fcg[(size_t)t * 64 + dbase + 1];
            o = v * cth + sgn * w * sth;
          }
          size_t dst = (size_t)part * ((size_t)BHX * TB * HD)
                     + ((size_t)(b * NH + h) * TB + t) * HD + d;
          out[dst] = bfb(o);
        }
      }
    }
  }
}

// v [bh][T][64] -> vT [bh][64][T], 64x64 tiles. 256 threads, 2 chunks each way.
__global__ void transpose_v(const unsigned short* __restrict__ v,
                            unsigned short* __restrict__ vT) {
  int bh = blockIdx.y, t0 = blockIdx.x * 64;
  __shared__ __align__(16) unsigned short tile[64][72];
  int tid = threadIdx.x;
#pragma unroll
  for (int s = 0; s < 2; s++) {
    int cid = tid + 256 * s;
    int r = cid >> 3, c8 = (cid & 7) * 8;
    bf16x8 val = *(const bf16x8*)(v + ((size_t)bh * TB + t0 + r) * HD + c8);
    *(bf16x8*)&tile[r][c8] = val;
  }
  __syncthreads();
#pragma unroll
  for (int s = 0; s < 2; s++) {
    int cid = tid + 256 * s;
    int rr = cid >> 3, cc = (cid & 7) * 8;
    bf16x8 o;
#pragma unroll
    for (int i = 0; i < 8; i++) o[i] = (short)tile[cc + i][rr];
    *(bf16x8*)(vT + ((size_t)bh * HD + rr) * TB + t0 + cc) = o;
  }
}

// Flash attention fwd, causal. STATIC XCD-affine schedule.
// SWAPPED QK^T (T12 enabler): z = mfma(K, Q) -> lane holds 16 kv-samples of
// its OWN q-row (q = l4). Row max = lane tree + 2 shfl_xor; m/l/alpha are
// scalars; row-sum cross-lane reduce deferred to epilogue. P packed with
// v_cvt_pk_bf16_f32 and written as 4x ds_write_b64 into Ps[q=l4][kv] with
// 16B-slot-pair XOR (l4&7); PV = mfma(V^T-frag, P-frag) accumulating O^T
// (col=q), epilogue packs 4 consecutive d as one 8B store.
__global__ __launch_bounds__(256, 4) void flash_fwd(
    const unsigned short* __restrict__ q, const unsigned short* __restrict__ k,
    const unsigned short* __restrict__ vT, unsigned short* __restrict__ yb)
{
  __shared__ __align__(16) unsigned short Ks[2][4096];
  __shared__ __align__(16) unsigned short Vs[2][4096];
  __shared__ __align__(16) unsigned short Ps[4][16][64];  // [wave][q=l4][kv swz]

  const int tid = threadIdx.x, wid = tid >> 6, lane = tid & 63;
  const int g = lane >> 4, l4 = lane & 15;

  const int b = blockIdx.x;
  const int xcd = b & 7;
  const int idx = b >> 3;
  const int bh = (xcd << 3) | (idx & 7);
  const int pr = idx >> 3;

  const int off0 = tid << 4;
  const int row0 = off0 >> 7, sc0 = ((off0 >> 4) & 7) ^ (row0 & 7);
  const int off1 = off0 + 4096;
  const int row1 = off1 >> 7, sc1 = ((off1 >> 4) & 7) ^ (row1 & 7);
  const int koff0 = (row0 << 6) + (sc0 << 3);
  const int koff1 = (row1 << 6) + (sc1 << 3);
  const int voff0 = (row0 << 11) + (sc0 << 3);
  const int voff1 = (row1 << 11) + (sc1 << 3);

  const float SCL2 = 0.18033688011112042f;  // 1/8 * log2(e)
  const int l7 = l4 & 7;

  unsigned short* psrow = &Ps[wid][l4][0];
  const int woff0 = ((0 + (g >> 1)) ^ l7) * 8 + (g & 1) * 4;  // cb=0
  const int woff1 = ((2 + (g >> 1)) ^ l7) * 8 + (g & 1) * 4;  // cb=1
  const int woff2 = ((4 + (g >> 1)) ^ l7) * 8 + (g & 1) * 4;  // cb=2
  const int woff3 = ((6 + (g >> 1)) ^ l7) * 8 + (g & 1) * 4;  // cb=3
  const int roff0 = (g ^ l7) * 8;
  const int roff1 = ((4 + g) ^ l7) * 8;

  const unsigned short* kb = k  + ((size_t)bh << 17);
  const unsigned short* vb = vT + ((size_t)bh << 17);

#pragma unroll 1
  for (int sel = 0; sel < 2; sel++) {
    const int q64 = sel ? (31 - pr) : pr;
    const int qrow = q64 * 64 + wid * 16 + l4;

    bf16x8 qf0, qf1;
    {
      const unsigned short* qp = q + (((size_t)bh * TB + qrow) << 6);
      qf0 = *(const bf16x8*)(qp + g * 8);
      qf1 = *(const bf16x8*)(qp + 32 + g * 8);
    }

    float m_run = -1e30f, l_run = 0.f;
    f32x4 acc_o[4] = {};

    gld_lds16(kb + koff0, &Ks[0][off0 >> 1]);
    gld_lds16(kb + koff1, &Ks[0][off1 >> 1]);
    gld_lds16(vb + voff0, &Vs[0][off0 >> 1]);
    gld_lds16(vb + voff1, &Vs[0][off1 >> 1]);
    __syncthreads();

    for (int kt = 0; kt <= q64; kt++) {
      const int cur = kt & 1;
      if (kt < q64) {
        const int kadd = (kt + 1) << 12;
        const int vadd = (kt + 1) << 6;
        gld_lds16(kb + koff0 + kadd, &Ks[cur ^ 1][off0 >> 1]);
        gld_lds16(kb + koff1 + kadd, &Ks[cur ^ 1][off1 >> 1]);
        gld_lds16(vb + voff0 + vadd, &Vs[cur ^ 1][off0 >> 1]);
        gld_lds16(vb + voff1 + vadd, &Vs[cur ^ 1][off1 >> 1]);
      }
      const unsigned short* Kc = Ks[cur];
      const unsigned short* Vc = Vs[cur];

      // S^T = K Q^T: lane holds S[q=own row][kv = 16cb+4g+j].
      float sv[4][4];
      __builtin_amdgcn_s_setprio(1);
#pragma unroll
      for (int cb = 0; cb < 4; cb++) {
        const int r = cb * 16 + l4;
        const int sw = (r & 7) * 8;
        bf16x8 kb0 = *(const bf16x8*)&Kc[r * 64 + ((g * 8) ^ sw)];
        bf16x8 kb1 = *(const bf16x8*)&Kc[r * 64 + (((g + 4) * 8) ^ sw)];
        f32x4 z = {0.f, 0.f, 0.f, 0.f};
        z = __builtin_amdgcn_mfma_f32_16x16x32_bf16(kb0, qf0, z, 0, 0, 0);
        z = __builtin_amdgcn_mfma_f32_16x16x32_bf16(kb1, qf1, z, 0, 0, 0);
#pragma unroll
        for (int j = 0; j < 4; j++)
          sv[cb][j] = z[j] * SCL2;
      }
      __builtin_amdgcn_s_setprio(0);
      if (kt == q64) {   // diagonal tile: mask kv > q  <=>  16cb+4g+j > wid*16+l4
        const int rq = wid * 16 + l4;
#pragma unroll
        for (int cb = 0; cb < 4; cb++)
#pragma unroll
          for (int j = 0; j < 4; j++)
            if (cb * 16 + 4 * g + j > rq) sv[cb][j] = -1e30f;
      }

      // Row max: lane-local tree + 2 shfl_xor across g-groups.
      float mt;
      {
        float m0 = fmaxf(fmaxf(sv[0][0], sv[0][1]), fmaxf(sv[0][2], sv[0][3]));
        float m1 = fmaxf(fmaxf(sv[1][0], sv[1][1]), fmaxf(sv[1][2], sv[1][3]));
        float m2 = fmaxf(fmaxf(sv[2][0], sv[2][1]), fmaxf(sv[2][2], sv[2][3]));
        float m3 = fmaxf(fmaxf(sv[3][0], sv[3][1]), fmaxf(sv[3][2], sv[3][3]));
        mt = fmaxf(fmaxf(m0, m1), fmaxf(m2, m3));
        mt = fmaxf(mt, __shfl_xor(mt, 16, 64));
        mt = fmaxf(mt, __shfl_xor(mt, 32, 64));
      }
      // Defer-max: rescale only when max grew by > 8 (log2 domain).
      bool need = mt > m_run + 8.f;
      if (__any(need)) {
        float mn = fmaxf(m_run, mt);
        float alpha = fexp2(m_run - mn);
        m_run = mn;
        l_run *= alpha;
#pragma unroll
        for (int db = 0; db < 4; db++)
#pragma unroll
          for (int j = 0; j < 4; j++) acc_o[db][j] *= alpha;
      }
      // exp + lane-local sum; pack P and write 4x ds_write_b64.
      float lsum = 0.f;
#pragma unroll
      for (int cb = 0; cb < 4; cb++) {
        float p0 = fexp2(sv[cb][0] - m_run);
        float p1 = fexp2(sv[cb][1] - m_run);
        float p2 = fexp2(sv[cb][2] - m_run);
        float p3 = fexp2(sv[cb][3] - m_run);
        lsum += (p0 + p1) + (p2 + p3);
        uint2 w;
        w.x = cvtpk(p0, p1);
        w.y = cvtpk(p2, p3);
        const int wo = (cb == 0) ? woff0 : (cb == 1) ? woff1 : (cb == 2) ? woff2 : woff3;
        *(uint2*)&psrow[wo] = w;
      }
      l_run += lsum;

      asm volatile("s_waitcnt lgkmcnt(0)" ::: "memory");
      __builtin_amdgcn_sched_barrier(0);
      bf16x8 pb0 = *(const bf16x8*)&psrow[roff0];
      bf16x8 pb1 = *(const bf16x8*)&psrow[roff1];
      __builtin_amdgcn_s_setprio(1);
#pragma unroll
      for (int db = 0; db < 4; db++) {
        const int r = db * 16 + l4;
        const int sw = (r & 7) * 8;
        bf16x8 vb0 = *(const bf16x8*)&Vc[r * 64 + ((g * 8) ^ sw)];
        bf16x8 vb1 = *(const bf16x8*)&Vc[r * 64 + (((g + 4) * 8) ^ sw)];
        acc_o[db] = __builtin_amdgcn_mfma_f32_16x16x32_bf16(vb0, pb0, acc_o[db], 0, 0, 0);
        acc_o[db] = __builtin_amdgcn_mfma_f32_16x16x32_bf16(vb1, pb1, acc_o[db], 0, 0, 0);
      }
      __builtin_amdgcn_s_setprio(0);
      __syncthreads();
    }

    // Epilogue: finish l across g-groups, normalize, write O^T rows.
    float l = l_run;
    l += __shfl_xor(l, 16, 64);
    l += __shfl_xor(l, 32, 64);
    const float inv = 1.0f / l;
    unsigned short* yp = yb + ((size_t)(bh >> 4) * TB) * CC + (size_t)(bh & 15) * HD;
#pragma unroll
    for (int db = 0; db < 4; db++) {
      us4 ov;
#pragma unroll
      for (int j = 0; j < 4; j++) ov[j] = bfb(acc_o[db][j] * inv);
      *(us4*)&yp[(size_t)qrow * CC + db * 16 + 4 * g] = ov;
    }
  }
}

extern "C" void kernel_launch(void* const* d_in, const int* in_sizes, int n_in,
                              void* d_out, int out_size, void* d_ws, size_t ws_size,
                              hipStream_t stream) {
  (void)in_sizes; (void)n_in; (void)out_size; (void)ws_size;
  const float* x  = (const float*)d_in[0];
  const float* fc = (const float*)d_in[1];
  // d_in[2]=attn_mask (tril), d_in[3]=padding_mask (all ones): applied analytically.
  const float* Wq = (const float*)d_in[4];
  const float* bq = (const float*)d_in[5];
  const float* Wk = (const float*)d_in[6];
  const float* bk = (const float*)d_in[7];
  const float* Wv = (const float*)d_in[8];
  const float* bv = (const float*)d_in[9];
  const float* Wp = (const float*)d_in[10];
  const float* bp = (const float*)d_in[11];

  char* ws = (char*)d_ws;
  unsigned short* xb   = (unsigned short*)(ws + 0);          // 8192x1024 bf16 (later reused as yb)
  unsigned short* wqkv = (unsigned short*)(ws + 16777216);   // 3072x1024 bf16
  unsigned short* wp   = (unsigned short*)(ws + 23068672);   // 1024x1024 bf16
  float*          bqkv = (float*)(ws + 25165824);            // 3072 f32
  unsigned short* qkv  = (unsigned short*)(ws + 25182208);   // 3 x [64][2048][64] bf16
  unsigned short* vT   = qkv + 3 * (size_t)8388608;          // [64][64][2048] bf16
  unsigned short* yb   = xb;

  cvt_f32_bf16<<<(2097152 + 255) / 256, 256, 0, stream>>>(x, xb, 2097152);
  cvt_w4<<<dim3(1024, 4), 256, 0, stream>>>(Wq, Wk, Wv, Wp,
      wqkv, wqkv + 1048576, wqkv + 2097152, wp);
  prep_bias<<<dim3(12), 256, 0, stream>>>(bq, bk, bv, bqkv);

  gemm_bt<1><<<dim3(1536), 512, 0, stream>>>(xb, wqkv, bqkv, fc, qkv, BTX, 3072, 1024, 24);
  transpose_v<<<dim3(32, 64), 256, 0, stream>>>(qkv + 2 * (size_t)8388608, vT);
  flash_fwd<<<dim3(1024), 256, 0, stream>>>(qkv, qkv + (size_t)8388608, vT, yb);
  gemm_bt<0><<<dim3(512), 512, 0, stream>>>(yb, wp, bp, nullptr, (float*)d_out, BTX, 1024, 1024, 8);
}